// Round 12
// baseline (116.021 us; speedup 1.0000x reference)
//
#include <hip/hip_runtime.h>
#include <math.h>

#define NPATCH 2048
#define NPTS 1024
#define NTOT (NPATCH * NPTS)

using f4 = __attribute__((ext_vector_type(4))) float;

__device__ __forceinline__ void nt_store4(float* p, float a, float b, float c, float d) {
    f4 v = {a, b, c, d};
    __builtin_nontemporal_store(v, reinterpret_cast<f4*>(p));
}
__device__ __forceinline__ void nt_copy4(float* dst, const float* src) {
    f4 v = *reinterpret_cast<const f4*>(src);
    __builtin_nontemporal_store(v, reinterpret_cast<f4*>(dst));
}
__device__ __forceinline__ void nt_store1(float* p, float v) {
    __builtin_nontemporal_store(v, p);
}

// ---------------------------------------------------------------------------
// Single mega-kernel: 8192 blocks x 256 threads, one quarter-patch each.
// R12 changes (LDS-traffic cut ~2x, everything else R11):
//   - area pass loop-swap: thread owns u-row, loops j  (36 -> 17 f4 reads)
//   - SH stage2: 192 threads own (i,c,js), tmp rows in regs, 16-j loop
//     (48 -> 20 f4 reads; stores in 192B contiguous chunks)
// ---------------------------------------------------------------------------
__global__ __launch_bounds__(256) void mega_kernel(
    const float* __restrict__ cp,       // [P,4,4,3]
    const float* __restrict__ Wt,       // [P,4,4]
    const float* __restrict__ sh_dc,    // [P,4,4,1,3]
    const float* __restrict__ sh_rest,  // [P,4,4,15,3]
    const float* __restrict__ spar,     // [P,2]
    const float* __restrict__ opac,     // [N,1]
    const float* __restrict__ b_u,      // [P,32,4]
    const float* __restrict__ b_v,
    const float* __restrict__ db_u,
    const float* __restrict__ db_v,
    const float* __restrict__ ddb_u,
    const float* __restrict__ ddb_v,
    float* __restrict__ out)
{
    const int blk = blockIdx.x;
    const int a = blk >> 2, q = blk & 3;
    const int t = threadIdx.x;

    __shared__ float s_W[16];
    __shared__ __align__(16) float s_wcp4[16][4];
    __shared__ __align__(16) float s_bu[32][4];     // full patch rows
    __shared__ __align__(16) float s_dbu[32][4];    // full patch rows
    __shared__ __align__(16) float s_ddbu[8][4];    // this quarter's rows
    __shared__ __align__(16) float s_bv[32][4];
    __shared__ __align__(16) float s_dbv[32][4];
    __shared__ __align__(16) float s_ddbv[32][4];
    __shared__ __align__(16) float s_tB[128][4];    // [i*4+l][m], i = 0..31
    __shared__ __align__(16) float s_tD[128][4];
    __shared__ __align__(16) float s_tE[32][4];     // local 8 rows
    __shared__ __align__(16) float s_wB[128];
    __shared__ __align__(16) float s_sh[16][48];
    __shared__ __align__(16) float s_tmp[8 * 208];  // [i][l][cq]: i*208+l*52+cq*4
    __shared__ float s_red[4];
    __shared__ float s_area;

    // ---- staging ----
    if (t < 16) {
        const float w = Wt[a * 16 + t];
        s_W[t] = w;
        s_wcp4[t][0] = cp[a * 48 + t * 3 + 0] * w;
        s_wcp4[t][1] = cp[a * 48 + t * 3 + 1] * w;
        s_wcp4[t][2] = cp[a * 48 + t * 3 + 2] * w;
        s_wcp4[t][3] = 0.f;
    }
    if (t < 128) {
        s_bu  [t >> 2][t & 3] = b_u  [a * 128 + t];
        s_dbu [t >> 2][t & 3] = db_u [a * 128 + t];
        s_bv  [t >> 2][t & 3] = b_v  [a * 128 + t];
        s_dbv [t >> 2][t & 3] = db_v [a * 128 + t];
        s_ddbv[t >> 2][t & 3] = ddb_v[a * 128 + t];
    }
    if (t < 32)
        s_ddbu[t >> 2][t & 3] = ddb_u[a * 128 + q * 32 + t];
    for (int idx = t; idx < 768; idx += 256) {
        const int kl = idx / 48, c = idx - kl * 48;
        s_sh[kl][c] = (c < 3) ? sh_dc[a * 48 + kl * 3 + c]
                              : sh_rest[a * 720 + kl * 45 + (c - 3)];
    }
    __syncthreads();

    // ---- stage 1 ----
    if (t < 128) {          // tB + wB for all 32 u-rows
        const int i = t >> 2, l = t & 3;
        f4 acc = {0.f, 0.f, 0.f, 0.f};
        float wa = 0.f;
        #pragma unroll
        for (int k = 0; k < 4; ++k) {
            const float b = s_bu[i][k];
            acc += b * *reinterpret_cast<const f4*>(s_wcp4[k * 4 + l]);
            wa  += b * s_W[k * 4 + l];
        }
        *reinterpret_cast<f4*>(s_tB[t]) = acc;
        s_wB[t] = wa;
    } else {                // tD for all 32 u-rows
        const int tt = t - 128, i = tt >> 2, l = tt & 3;
        f4 acc = {0.f, 0.f, 0.f, 0.f};
        #pragma unroll
        for (int k = 0; k < 4; ++k)
            acc += s_dbu[i][k] * *reinterpret_cast<const f4*>(s_wcp4[k * 4 + l]);
        *reinterpret_cast<f4*>(s_tD[tt]) = acc;
    }
    if (t < 32) {           // tE for this quarter's 8 rows
        const int i = t >> 2, l = t & 3;
        f4 acc = {0.f, 0.f, 0.f, 0.f};
        #pragma unroll
        for (int k = 0; k < 4; ++k)
            acc += s_ddbu[i][k] * *reinterpret_cast<const f4*>(s_wcp4[k * 4 + l]);
        *reinterpret_cast<f4*>(s_tE[t]) = acc;
    }
    // SH stage1: tmp[i][l][cq] for this quarter's 8 rows (384 float4)
    #pragma unroll
    for (int r = 0; r < 2; ++r) {
        const int e4 = t + r * 256;
        if (e4 < 384) {
            const int i = e4 / 48, rem = e4 - i * 48;
            const int l = rem / 12, cq = rem - l * 12;
            float ax = 0.f, ay = 0.f, az = 0.f, aw = 0.f;
            #pragma unroll
            for (int k = 0; k < 4; ++k) {
                const float w = s_bu[q * 8 + i][k];
                const float4 v = *reinterpret_cast<const float4*>(&s_sh[k * 4 + l][cq * 4]);
                ax += w * v.x; ay += w * v.y; az += w * v.z; aw += w * v.w;
            }
            *reinterpret_cast<float4*>(&s_tmp[i * 208 + l * 52 + cq * 4]) =
                make_float4(ax, ay, az, aw);
        }
    }
    __syncthreads();

    // ---- full-patch area pass (loop-swapped): thread owns row ia, loops j ----
    {
        const int ia = t >> 3;          // 0..31
        const int jb = t & 7;           // j base
        const f4 tb0 = *reinterpret_cast<const f4*>(s_tB[ia * 4 + 0]);
        const f4 tb1 = *reinterpret_cast<const f4*>(s_tB[ia * 4 + 1]);
        const f4 tb2 = *reinterpret_cast<const f4*>(s_tB[ia * 4 + 2]);
        const f4 tb3 = *reinterpret_cast<const f4*>(s_tB[ia * 4 + 3]);
        const f4 td0 = *reinterpret_cast<const f4*>(s_tD[ia * 4 + 0]);
        const f4 td1 = *reinterpret_cast<const f4*>(s_tD[ia * 4 + 1]);
        const f4 td2 = *reinterpret_cast<const f4*>(s_tD[ia * 4 + 2]);
        const f4 td3 = *reinterpret_cast<const f4*>(s_tD[ia * 4 + 3]);
        const f4 wb  = *(reinterpret_cast<const f4*>(s_wB) + ia);

        float acc = 0.f;
        #pragma unroll
        for (int s2 = 0; s2 < 4; ++s2) {
            const int j = jb + 8 * s2;
            const f4 bv  = *reinterpret_cast<const f4*>(s_bv[j]);
            const f4 dbv = *reinterpret_cast<const f4*>(s_dbv[j]);

            float den = bv.x * wb.x + bv.y * wb.y + bv.z * wb.z + bv.w * wb.w;
            if (den == 0.f) den = 1.f;
            const float inv = 1.0f / den;

            const f4 du = bv.x  * td0 + bv.y  * td1 + bv.z  * td2 + bv.w  * td3;
            const f4 dv = dbv.x * tb0 + dbv.y * tb1 + dbv.z * tb2 + dbv.w * tb3;

            const float cx = du.y * dv.z - du.z * dv.y;
            const float cy = du.z * dv.x - du.x * dv.z;
            const float cz = du.x * dv.y - du.y * dv.x;
            acc += sqrtf(cx * cx + cy * cy + cz * cz) * inv * inv;
        }
        #pragma unroll
        for (int off = 32; off > 0; off >>= 1)
            acc += __shfl_down(acc, off, 64);
        if ((t & 63) == 0) s_red[t >> 6] = acc;
    }
    __syncthreads();
    if (t == 0) s_area = s_red[0] + s_red[1] + s_red[2] + s_red[3];
    __syncthreads();

    const long N3 = 3L * NTOT, N4 = 4L * NTOT, N7 = 7L * NTOT;
    const long n0 = (long)a * NPTS + q * 256;
    const long n  = n0 + t;

    // ---- geometry stage 2 (direct NT stores) ----
    {
        const int j  = t & 31;
        const int gi = q * 8 + (t >> 5);        // global u-row
        const f4 bvJ   = *reinterpret_cast<const f4*>(s_bv[j]);
        const f4 dbvJ  = *reinterpret_cast<const f4*>(s_dbv[j]);
        const f4 ddbvJ = *reinterpret_cast<const f4*>(s_ddbv[j]);

        const f4 tb0 = *reinterpret_cast<const f4*>(s_tB[gi * 4 + 0]);
        const f4 tb1 = *reinterpret_cast<const f4*>(s_tB[gi * 4 + 1]);
        const f4 tb2 = *reinterpret_cast<const f4*>(s_tB[gi * 4 + 2]);
        const f4 tb3 = *reinterpret_cast<const f4*>(s_tB[gi * 4 + 3]);
        const f4 td0 = *reinterpret_cast<const f4*>(s_tD[gi * 4 + 0]);
        const f4 td1 = *reinterpret_cast<const f4*>(s_tD[gi * 4 + 1]);
        const f4 td2 = *reinterpret_cast<const f4*>(s_tD[gi * 4 + 2]);
        const f4 td3 = *reinterpret_cast<const f4*>(s_tD[gi * 4 + 3]);
        const int il = t >> 5;                  // local row for tE
        const f4 te0 = *reinterpret_cast<const f4*>(s_tE[il * 4 + 0]);
        const f4 te1 = *reinterpret_cast<const f4*>(s_tE[il * 4 + 1]);
        const f4 te2 = *reinterpret_cast<const f4*>(s_tE[il * 4 + 2]);
        const f4 te3 = *reinterpret_cast<const f4*>(s_tE[il * 4 + 3]);
        const f4 wb  = *(reinterpret_cast<const f4*>(s_wB) + gi);

        float den = bvJ.x * wb.x + bvJ.y * wb.y + bvJ.z * wb.z + bvJ.w * wb.w;
        if (den == 0.f) den = 1.f;
        const float inv = 1.0f / den;

        const f4 xyz = bvJ.x  * tb0 + bvJ.y  * tb1 + bvJ.z  * tb2 + bvJ.w  * tb3;
        const f4 du  = bvJ.x  * td0 + bvJ.y  * td1 + bvJ.z  * td2 + bvJ.w  * td3;
        const f4 dv  = dbvJ.x * tb0 + dbvJ.y * tb1 + dbvJ.z * tb2 + dbvJ.w * tb3;
        const f4 eu  = bvJ.x  * te0 + bvJ.y  * te1 + bvJ.z  * te2 + bvJ.w  * te3;
        const f4 ev  = ddbvJ.x* tb0 + ddbvJ.y* tb1 + ddbvJ.z* tb2 + ddbvJ.w* tb3;

        const float x0 = xyz.x * inv, x1 = xyz.y * inv, x2 = xyz.z * inv;
        const float du0 = du.x * inv, du1 = du.y * inv, du2 = du.z * inv;
        const float dv0 = dv.x * inv, dv1 = dv.y * inv, dv2 = dv.z * inv;

        const float cx = du1 * dv2 - du2 * dv1;
        const float cy = du2 * dv0 - du0 * dv2;
        const float cz = du0 * dv1 - du1 * dv0;

        // n = cross / ||cross||_2  (L1 normalize is mathematically dead)
        const float clen = sqrtf(cx * cx + cy * cy + cz * cz);
        const float rcl  = 1.0f / fmaxf(clen, 1e-20f);
        const float nx = cx * rcl, ny = cy * rcl, nz = cz * rcl;
        const float qw = 1.f + nz, qx = -ny, qy = nx;
        float qn = sqrtf(qw * qw + qx * qx + qy * qy);
        qn = fmaxf(qn, 1e-12f);
        const float rqn = 1.0f / qn;

        nt_store4(out + N7 + n * 4, qw * rqn, qx * rqn, qy * rqn, 0.f);
        nt_store1(out + n * 3 + 0, x0);
        nt_store1(out + n * 3 + 1, x1);
        nt_store1(out + n * 3 + 2, x2);

        if (t < 64)
            nt_copy4(out + N3 + n0 + 4 * t, opac + n0 + 4 * t);

        const float sx  = du0 * du0 + du1 * du1 + du2 * du2 + 10.f;
        const float sy  = dv0 * dv0 + dv1 * dv1 + dv2 * dv2 + 10.f;
        const float cvx = (eu.x + eu.y + eu.z) * inv;
        const float cvy = (ev.x + ev.y + ev.z) * inv;

        const float factor = s_area * (1.0f / 1024.0f) * (1.0f / 1024.0f);
        const float sp0 = spar[a * 2 + 0], sp1 = spar[a * 2 + 1];
        const float sf0 = factor * sp0;
        const float sf1 = factor * sp1;
        const float sf2 = factor * 1e-16f;

        nt_store1(out + N4 + n * 3 + 0,
                  0.5f * __logf(fabsf(sf0 * sx)) - __logf(fabsf(cvx) + 10.f));
        nt_store1(out + N4 + n * 3 + 1,
                  0.5f * __logf(fabsf(sf1 * sy)) - __logf(fabsf(cvy) + 10.f));
        nt_store1(out + N4 + n * 3 + 2,
                  0.5f * __logf(fabsf(sf2 * 10.f)) - __logf(11.f));
    }

    // ---- SH stage 2: 192 threads own (i,c,js); tmp rows in registers ----
    if (t < 192) {
        const int i  = t / 24;          // 0..7  (local u-row)
        const int rm = t - i * 24;
        const int c  = rm >> 1;         // 0..11
        const int js = rm & 1;          // j half: 0 -> j 0..15, 1 -> j 16..31

        const float* base = &s_tmp[i * 208 + c * 4];
        const f4 t0 = *reinterpret_cast<const f4*>(base + 0 * 52);
        const f4 t1 = *reinterpret_cast<const f4*>(base + 1 * 52);
        const f4 t2 = *reinterpret_cast<const f4*>(base + 2 * 52);
        const f4 t3 = *reinterpret_cast<const f4*>(base + 3 * 52);

        float* __restrict__ outp =
            out + 11L * NTOT + ((long)a * 12288 + q * 3072) * 4;

        #pragma unroll 4
        for (int jj = 0; jj < 16; ++jj) {
            const int j = js * 16 + jj;
            const f4 bv = *reinterpret_cast<const f4*>(s_bv[j]);
            nt_store4(outp + (((i * 32 + j) * 12) + c) * 4,
                bv.x * t0.x + bv.y * t1.x + bv.z * t2.x + bv.w * t3.x,
                bv.x * t0.y + bv.y * t1.y + bv.z * t2.y + bv.w * t3.y,
                bv.x * t0.z + bv.y * t1.z + bv.z * t2.z + bv.w * t3.z,
                bv.x * t0.w + bv.y * t1.w + bv.z * t2.w + bv.w * t3.w);
        }
    }
}

extern "C" void kernel_launch(void* const* d_in, const int* in_sizes, int n_in,
                              void* d_out, int out_size, void* d_ws, size_t ws_size,
                              hipStream_t stream) {
    const float* cp      = (const float*)d_in[0];
    const float* Wt      = (const float*)d_in[1];
    const float* sh_dc   = (const float*)d_in[2];
    const float* sh_rest = (const float*)d_in[3];
    const float* spar    = (const float*)d_in[4];
    const float* opac    = (const float*)d_in[5];
    const float* b_u     = (const float*)d_in[6];
    const float* b_v     = (const float*)d_in[7];
    const float* db_u    = (const float*)d_in[8];
    const float* db_v    = (const float*)d_in[9];
    const float* ddb_u   = (const float*)d_in[10];
    const float* ddb_v   = (const float*)d_in[11];
    float* out = (float*)d_out;

    hipLaunchKernelGGL(mega_kernel, dim3(NPATCH * 4), dim3(256), 0, stream,
                       cp, Wt, sh_dc, sh_rest, spar, opac,
                       b_u, b_v, db_u, db_v, ddb_u, ddb_v, out);
}

// Round 13
// 100.322 us; speedup vs baseline: 1.1565x; 1.1565x over previous
//
#include <hip/hip_runtime.h>
#include <math.h>

#define NPATCH 2048
#define NPTS 1024
#define NTOT (NPATCH * NPTS)

using f4 = __attribute__((ext_vector_type(4))) float;

__device__ __forceinline__ void nt_store4(float* p, float a, float b, float c, float d) {
    f4 v = {a, b, c, d};
    __builtin_nontemporal_store(v, reinterpret_cast<f4*>(p));
}
__device__ __forceinline__ void nt_copy4(float* dst, const float* src) {
    f4 v = *reinterpret_cast<const f4*>(src);
    __builtin_nontemporal_store(v, reinterpret_cast<f4*>(dst));
}
__device__ __forceinline__ void nt_store1(float* p, float v) {
    __builtin_nontemporal_store(v, p);
}

// ---------------------------------------------------------------------------
// Single mega-kernel: 8192 blocks x 256 threads, one quarter-patch each.
// R13 = R11 + area loop-swap ONLY (SH stage-2 reverted to R11's perfectly
// wave-contiguous mapping; R12 showed store scatter there costs more than
// LDS reads save).
// ---------------------------------------------------------------------------
__global__ __launch_bounds__(256) void mega_kernel(
    const float* __restrict__ cp,       // [P,4,4,3]
    const float* __restrict__ Wt,       // [P,4,4]
    const float* __restrict__ sh_dc,    // [P,4,4,1,3]
    const float* __restrict__ sh_rest,  // [P,4,4,15,3]
    const float* __restrict__ spar,     // [P,2]
    const float* __restrict__ opac,     // [N,1]
    const float* __restrict__ b_u,      // [P,32,4]
    const float* __restrict__ b_v,
    const float* __restrict__ db_u,
    const float* __restrict__ db_v,
    const float* __restrict__ ddb_u,
    const float* __restrict__ ddb_v,
    float* __restrict__ out)
{
    const int blk = blockIdx.x;
    const int a = blk >> 2, q = blk & 3;
    const int t = threadIdx.x;

    __shared__ float s_W[16];
    __shared__ __align__(16) float s_wcp4[16][4];
    __shared__ __align__(16) float s_bu[32][4];     // full patch rows
    __shared__ __align__(16) float s_dbu[32][4];    // full patch rows
    __shared__ __align__(16) float s_ddbu[8][4];    // this quarter's rows
    __shared__ __align__(16) float s_bv[32][4];
    __shared__ __align__(16) float s_dbv[32][4];
    __shared__ __align__(16) float s_ddbv[32][4];
    __shared__ __align__(16) float s_tB[128][4];    // [i*4+l][m], i = 0..31
    __shared__ __align__(16) float s_tD[128][4];
    __shared__ __align__(16) float s_tE[32][4];     // local 8 rows
    __shared__ __align__(16) float s_wB[128];
    __shared__ __align__(16) float s_sh[16][48];
    __shared__ __align__(16) float s_tmp[8 * 208];  // [i][l][cq]: i*208+l*52+cq*4
    __shared__ float s_red[4];
    __shared__ float s_area;

    // ---- staging ----
    if (t < 16) {
        const float w = Wt[a * 16 + t];
        s_W[t] = w;
        s_wcp4[t][0] = cp[a * 48 + t * 3 + 0] * w;
        s_wcp4[t][1] = cp[a * 48 + t * 3 + 1] * w;
        s_wcp4[t][2] = cp[a * 48 + t * 3 + 2] * w;
        s_wcp4[t][3] = 0.f;
    }
    if (t < 128) {
        s_bu  [t >> 2][t & 3] = b_u  [a * 128 + t];
        s_dbu [t >> 2][t & 3] = db_u [a * 128 + t];
        s_bv  [t >> 2][t & 3] = b_v  [a * 128 + t];
        s_dbv [t >> 2][t & 3] = db_v [a * 128 + t];
        s_ddbv[t >> 2][t & 3] = ddb_v[a * 128 + t];
    }
    if (t < 32)
        s_ddbu[t >> 2][t & 3] = ddb_u[a * 128 + q * 32 + t];
    for (int idx = t; idx < 768; idx += 256) {
        const int kl = idx / 48, c = idx - kl * 48;
        s_sh[kl][c] = (c < 3) ? sh_dc[a * 48 + kl * 3 + c]
                              : sh_rest[a * 720 + kl * 45 + (c - 3)];
    }
    __syncthreads();

    // ---- stage 1 ----
    if (t < 128) {          // tB + wB for all 32 u-rows
        const int i = t >> 2, l = t & 3;
        f4 acc = {0.f, 0.f, 0.f, 0.f};
        float wa = 0.f;
        #pragma unroll
        for (int k = 0; k < 4; ++k) {
            const float b = s_bu[i][k];
            acc += b * *reinterpret_cast<const f4*>(s_wcp4[k * 4 + l]);
            wa  += b * s_W[k * 4 + l];
        }
        *reinterpret_cast<f4*>(s_tB[t]) = acc;
        s_wB[t] = wa;
    } else {                // tD for all 32 u-rows
        const int tt = t - 128, i = tt >> 2, l = tt & 3;
        f4 acc = {0.f, 0.f, 0.f, 0.f};
        #pragma unroll
        for (int k = 0; k < 4; ++k)
            acc += s_dbu[i][k] * *reinterpret_cast<const f4*>(s_wcp4[k * 4 + l]);
        *reinterpret_cast<f4*>(s_tD[tt]) = acc;
    }
    if (t < 32) {           // tE for this quarter's 8 rows
        const int i = t >> 2, l = t & 3;
        f4 acc = {0.f, 0.f, 0.f, 0.f};
        #pragma unroll
        for (int k = 0; k < 4; ++k)
            acc += s_ddbu[i][k] * *reinterpret_cast<const f4*>(s_wcp4[k * 4 + l]);
        *reinterpret_cast<f4*>(s_tE[t]) = acc;
    }
    // SH stage1: tmp[i][l][cq] for this quarter's 8 rows (384 float4)
    #pragma unroll
    for (int r = 0; r < 2; ++r) {
        const int e4 = t + r * 256;
        if (e4 < 384) {
            const int i = e4 / 48, rem = e4 - i * 48;
            const int l = rem / 12, cq = rem - l * 12;
            float ax = 0.f, ay = 0.f, az = 0.f, aw = 0.f;
            #pragma unroll
            for (int k = 0; k < 4; ++k) {
                const float w = s_bu[q * 8 + i][k];
                const float4 v = *reinterpret_cast<const float4*>(&s_sh[k * 4 + l][cq * 4]);
                ax += w * v.x; ay += w * v.y; az += w * v.z; aw += w * v.w;
            }
            *reinterpret_cast<float4*>(&s_tmp[i * 208 + l * 52 + cq * 4]) =
                make_float4(ax, ay, az, aw);
        }
    }
    __syncthreads();

    // ---- full-patch area pass (loop-swapped): thread owns row ia, loops j ----
    {
        const int ia = t >> 3;          // 0..31
        const int jb = t & 7;           // j base
        const f4 tb0 = *reinterpret_cast<const f4*>(s_tB[ia * 4 + 0]);
        const f4 tb1 = *reinterpret_cast<const f4*>(s_tB[ia * 4 + 1]);
        const f4 tb2 = *reinterpret_cast<const f4*>(s_tB[ia * 4 + 2]);
        const f4 tb3 = *reinterpret_cast<const f4*>(s_tB[ia * 4 + 3]);
        const f4 td0 = *reinterpret_cast<const f4*>(s_tD[ia * 4 + 0]);
        const f4 td1 = *reinterpret_cast<const f4*>(s_tD[ia * 4 + 1]);
        const f4 td2 = *reinterpret_cast<const f4*>(s_tD[ia * 4 + 2]);
        const f4 td3 = *reinterpret_cast<const f4*>(s_tD[ia * 4 + 3]);
        const f4 wb  = *(reinterpret_cast<const f4*>(s_wB) + ia);

        float acc = 0.f;
        #pragma unroll
        for (int s2 = 0; s2 < 4; ++s2) {
            const int j = jb + 8 * s2;
            const f4 bv  = *reinterpret_cast<const f4*>(s_bv[j]);
            const f4 dbv = *reinterpret_cast<const f4*>(s_dbv[j]);

            float den = bv.x * wb.x + bv.y * wb.y + bv.z * wb.z + bv.w * wb.w;
            if (den == 0.f) den = 1.f;
            const float inv = 1.0f / den;

            const f4 du = bv.x  * td0 + bv.y  * td1 + bv.z  * td2 + bv.w  * td3;
            const f4 dv = dbv.x * tb0 + dbv.y * tb1 + dbv.z * tb2 + dbv.w * tb3;

            const float cx = du.y * dv.z - du.z * dv.y;
            const float cy = du.z * dv.x - du.x * dv.z;
            const float cz = du.x * dv.y - du.y * dv.x;
            acc += sqrtf(cx * cx + cy * cy + cz * cz) * inv * inv;
        }
        #pragma unroll
        for (int off = 32; off > 0; off >>= 1)
            acc += __shfl_down(acc, off, 64);
        if ((t & 63) == 0) s_red[t >> 6] = acc;
    }
    __syncthreads();
    if (t == 0) s_area = s_red[0] + s_red[1] + s_red[2] + s_red[3];
    __syncthreads();

    const long N3 = 3L * NTOT, N4 = 4L * NTOT, N7 = 7L * NTOT;
    const long n0 = (long)a * NPTS + q * 256;
    const long n  = n0 + t;

    // ---- geometry stage 2 (direct NT stores) ----
    {
        const int j  = t & 31;
        const int gi = q * 8 + (t >> 5);        // global u-row
        const f4 bvJ   = *reinterpret_cast<const f4*>(s_bv[j]);
        const f4 dbvJ  = *reinterpret_cast<const f4*>(s_dbv[j]);
        const f4 ddbvJ = *reinterpret_cast<const f4*>(s_ddbv[j]);

        const f4 tb0 = *reinterpret_cast<const f4*>(s_tB[gi * 4 + 0]);
        const f4 tb1 = *reinterpret_cast<const f4*>(s_tB[gi * 4 + 1]);
        const f4 tb2 = *reinterpret_cast<const f4*>(s_tB[gi * 4 + 2]);
        const f4 tb3 = *reinterpret_cast<const f4*>(s_tB[gi * 4 + 3]);
        const f4 td0 = *reinterpret_cast<const f4*>(s_tD[gi * 4 + 0]);
        const f4 td1 = *reinterpret_cast<const f4*>(s_tD[gi * 4 + 1]);
        const f4 td2 = *reinterpret_cast<const f4*>(s_tD[gi * 4 + 2]);
        const f4 td3 = *reinterpret_cast<const f4*>(s_tD[gi * 4 + 3]);
        const int il = t >> 5;                  // local row for tE
        const f4 te0 = *reinterpret_cast<const f4*>(s_tE[il * 4 + 0]);
        const f4 te1 = *reinterpret_cast<const f4*>(s_tE[il * 4 + 1]);
        const f4 te2 = *reinterpret_cast<const f4*>(s_tE[il * 4 + 2]);
        const f4 te3 = *reinterpret_cast<const f4*>(s_tE[il * 4 + 3]);
        const f4 wb  = *(reinterpret_cast<const f4*>(s_wB) + gi);

        float den = bvJ.x * wb.x + bvJ.y * wb.y + bvJ.z * wb.z + bvJ.w * wb.w;
        if (den == 0.f) den = 1.f;
        const float inv = 1.0f / den;

        const f4 xyz = bvJ.x  * tb0 + bvJ.y  * tb1 + bvJ.z  * tb2 + bvJ.w  * tb3;
        const f4 du  = bvJ.x  * td0 + bvJ.y  * td1 + bvJ.z  * td2 + bvJ.w  * td3;
        const f4 dv  = dbvJ.x * tb0 + dbvJ.y * tb1 + dbvJ.z * tb2 + dbvJ.w * tb3;
        const f4 eu  = bvJ.x  * te0 + bvJ.y  * te1 + bvJ.z  * te2 + bvJ.w  * te3;
        const f4 ev  = ddbvJ.x* tb0 + ddbvJ.y* tb1 + ddbvJ.z* tb2 + ddbvJ.w* tb3;

        const float x0 = xyz.x * inv, x1 = xyz.y * inv, x2 = xyz.z * inv;
        const float du0 = du.x * inv, du1 = du.y * inv, du2 = du.z * inv;
        const float dv0 = dv.x * inv, dv1 = dv.y * inv, dv2 = dv.z * inv;

        const float cx = du1 * dv2 - du2 * dv1;
        const float cy = du2 * dv0 - du0 * dv2;
        const float cz = du0 * dv1 - du1 * dv0;

        // n = cross / ||cross||_2  (L1 normalize is mathematically dead)
        const float clen = sqrtf(cx * cx + cy * cy + cz * cz);
        const float rcl  = 1.0f / fmaxf(clen, 1e-20f);
        const float nx = cx * rcl, ny = cy * rcl, nz = cz * rcl;
        const float qw = 1.f + nz, qx = -ny, qy = nx;
        float qn = sqrtf(qw * qw + qx * qx + qy * qy);
        qn = fmaxf(qn, 1e-12f);
        const float rqn = 1.0f / qn;

        nt_store4(out + N7 + n * 4, qw * rqn, qx * rqn, qy * rqn, 0.f);
        nt_store1(out + n * 3 + 0, x0);
        nt_store1(out + n * 3 + 1, x1);
        nt_store1(out + n * 3 + 2, x2);

        if (t < 64)
            nt_copy4(out + N3 + n0 + 4 * t, opac + n0 + 4 * t);

        const float sx  = du0 * du0 + du1 * du1 + du2 * du2 + 10.f;
        const float sy  = dv0 * dv0 + dv1 * dv1 + dv2 * dv2 + 10.f;
        const float cvx = (eu.x + eu.y + eu.z) * inv;
        const float cvy = (ev.x + ev.y + ev.z) * inv;

        const float factor = s_area * (1.0f / 1024.0f) * (1.0f / 1024.0f);
        const float sp0 = spar[a * 2 + 0], sp1 = spar[a * 2 + 1];
        const float sf0 = factor * sp0;
        const float sf1 = factor * sp1;
        const float sf2 = factor * 1e-16f;

        nt_store1(out + N4 + n * 3 + 0,
                  0.5f * __logf(fabsf(sf0 * sx)) - __logf(fabsf(cvx) + 10.f));
        nt_store1(out + N4 + n * 3 + 1,
                  0.5f * __logf(fabsf(sf1 * sy)) - __logf(fabsf(cvy) + 10.f));
        nt_store1(out + N4 + n * 3 + 2,
                  0.5f * __logf(fabsf(sf2 * 10.f)) - __logf(11.f));
    }

    // ---- SH stage 2 (R11 mapping: perfectly wave-contiguous stores) ----
    float* __restrict__ outp =
        out + 11L * NTOT + ((long)a * 12288 + q * 3072) * 4;

    #pragma unroll
    for (int k = 0; k < 12; ++k) {
        const unsigned f = t + (k << 8);
        const unsigned p = f / 12u;
        const unsigned c = f - p * 12u;
        const int i = p >> 5;
        const int jj = p & 31;

        const float4 bv = *reinterpret_cast<const float4*>(s_bv[jj]);
        const float* base = &s_tmp[i * 208 + c * 4];

        const float4 t0 = *reinterpret_cast<const float4*>(base + 0 * 52);
        const float4 t1 = *reinterpret_cast<const float4*>(base + 1 * 52);
        const float4 t2 = *reinterpret_cast<const float4*>(base + 2 * 52);
        const float4 t3 = *reinterpret_cast<const float4*>(base + 3 * 52);

        nt_store4(outp + f * 4,
            bv.x * t0.x + bv.y * t1.x + bv.z * t2.x + bv.w * t3.x,
            bv.x * t0.y + bv.y * t1.y + bv.z * t2.y + bv.w * t3.y,
            bv.x * t0.z + bv.y * t1.z + bv.z * t2.z + bv.w * t3.z,
            bv.x * t0.w + bv.y * t1.w + bv.z * t2.w + bv.w * t3.w);
    }
}

extern "C" void kernel_launch(void* const* d_in, const int* in_sizes, int n_in,
                              void* d_out, int out_size, void* d_ws, size_t ws_size,
                              hipStream_t stream) {
    const float* cp      = (const float*)d_in[0];
    const float* Wt      = (const float*)d_in[1];
    const float* sh_dc   = (const float*)d_in[2];
    const float* sh_rest = (const float*)d_in[3];
    const float* spar    = (const float*)d_in[4];
    const float* opac    = (const float*)d_in[5];
    const float* b_u     = (const float*)d_in[6];
    const float* b_v     = (const float*)d_in[7];
    const float* db_u    = (const float*)d_in[8];
    const float* db_v    = (const float*)d_in[9];
    const float* ddb_u   = (const float*)d_in[10];
    const float* ddb_v   = (const float*)d_in[11];
    float* out = (float*)d_out;

    hipLaunchKernelGGL(mega_kernel, dim3(NPATCH * 4), dim3(256), 0, stream,
                       cp, Wt, sh_dc, sh_rest, spar, opac,
                       b_u, b_v, db_u, db_v, ddb_u, ddb_v, out);
}